// Round 8
// baseline (442.518 us; speedup 1.0000x reference)
//
#include <hip/hip_runtime.h>
#include <hip/hip_fp16.h>

// N=100000 nodes, E=1600000 edges, F=128, G=1000 graphs.
#define FDIM 128
#define BROWS 64
#define KCH 16
#define NCH (FDIM / KCH)   // 8 chunks
#define BSHIFT 9           // 512 nodes per bucket
#define BNODES 512
#define EPB 4096           // edges per binscatter block
#define NSLICE 8           // feature slices (16 feats each); slice = bid % 8 -> XCD
#define SFEAT 16

// ---------------------------------------------------------------------------
// CSR build via two-level bucket binning (write-locality aware).
// ---------------------------------------------------------------------------

__global__ __launch_bounds__(256) void bucket_count(const int* __restrict__ dst,
                                                    int* __restrict__ bcnt, int E) {
    __shared__ int lc[256];
    lc[threadIdx.x] = 0;
    __syncthreads();
    for (int e = blockIdx.x * blockDim.x + threadIdx.x; e < E;
         e += gridDim.x * blockDim.x)
        atomicAdd(&lc[dst[e] >> BSHIFT], 1);
    __syncthreads();
    int c = lc[threadIdx.x];
    if (c) atomicAdd(&bcnt[threadIdx.x], c);
}

// single block: exclusive scan of bucket counts -> bbase, bcur; rp[n]=E.
__global__ void bucket_scan(const int* __restrict__ bcnt, int* __restrict__ bbase,
                            int* __restrict__ bcur, int* __restrict__ rp,
                            int E, int n, int nbuck) {
    __shared__ int s[2][256];
    int t = threadIdx.x;
    int v = (t < nbuck) ? bcnt[t] : 0;
    s[0][t] = v;
    __syncthreads();
    int cur = 0;
    for (int off = 1; off < 256; off <<= 1) {
        int x = s[cur][t];
        if (t >= off) x += s[cur][t - off];
        s[cur ^ 1][t] = x;
        cur ^= 1;
        __syncthreads();
    }
    int ex = s[cur][t] - v;
    if (t < nbuck) { bbase[t] = ex; bcur[t] = ex; }
    if (t == 0) { bbase[nbuck] = E; rp[n] = E; }
}

// Bin edges into bucket-ordered u32 buffer ebp[] with block-contiguous runs.
__global__ __launch_bounds__(256) void binscatter(const int* __restrict__ src,
                                                  const int* __restrict__ dst,
                                                  int* __restrict__ bcur,
                                                  unsigned* __restrict__ ebp, int E) {
    __shared__ int lcnt[256];
    __shared__ int gb[256];
    const int t = threadIdx.x;
    const int e0 = blockIdx.x * EPB;
    const int e1 = min(e0 + EPB, E);
    lcnt[t] = 0;
    __syncthreads();
    for (int e = e0 + t; e < e1; e += 256)
        atomicAdd(&lcnt[dst[e] >> BSHIFT], 1);
    __syncthreads();
    int c = lcnt[t];
    if (c) gb[t] = atomicAdd(&bcur[t], c);   // claim contiguous run per bucket
    __syncthreads();
    lcnt[t] = 0;
    __syncthreads();
    for (int e = e0 + t; e < e1; e += 256) {
        int d = dst[e];
        int b = d >> BSHIFT;
        int lo = atomicAdd(&lcnt[b], 1);
        ebp[gb[b] + lo] = ((unsigned)src[e] << BSHIFT) | (unsigned)(d & (BNODES - 1));
    }
}

// One block per bucket: degree count + LDS scan -> rp, dinv; then scatter
// src-only edge list em in CSR order; also graph-count histogram.
__global__ __launch_bounds__(256) void csr_build(const unsigned* __restrict__ ebp,
                                                 const int* __restrict__ bbase,
                                                 const int* __restrict__ batch,
                                                 int* __restrict__ rp,
                                                 float* __restrict__ dinv,
                                                 int* __restrict__ em,
                                                 int* __restrict__ gcnt, int n) {
    __shared__ int lcnt[BNODES];
    __shared__ int s[2][BNODES];
    __shared__ int lcur[BNODES];
    const int t = threadIdx.x;
    const int node0 = blockIdx.x << BSHIFT;
    const int nloc = min(BNODES, n - node0);
    lcnt[t] = 0; lcnt[t + 256] = 0;
    __syncthreads();
    const int eb0 = bbase[blockIdx.x], eb1 = bbase[blockIdx.x + 1];
    for (int e = eb0 + t; e < eb1; e += 256)
        atomicAdd(&lcnt[ebp[e] & (BNODES - 1)], 1);
    __syncthreads();
    s[0][t] = lcnt[t]; s[0][t + 256] = lcnt[t + 256];
    __syncthreads();
    int cur = 0;
    for (int off = 1; off < BNODES; off <<= 1) {
        int x0 = s[cur][t];       if (t >= off)       x0 += s[cur][t - off];
        int x1 = s[cur][t + 256]; if (t + 256 >= off) x1 += s[cur][t + 256 - off];
        s[cur ^ 1][t] = x0; s[cur ^ 1][t + 256] = x1;
        cur ^= 1;
        __syncthreads();
    }
    int ex0 = eb0 + s[cur][t] - lcnt[t];
    int ex1 = eb0 + s[cur][t + 256] - lcnt[t + 256];
    lcur[t] = ex0; lcur[t + 256] = ex1;
    if (t < nloc) {
        rp[node0 + t] = ex0;
        dinv[node0 + t] = rsqrtf((float)lcnt[t] + 1.0f);
    }
    if (t + 256 < nloc) {
        rp[node0 + t + 256] = ex1;
        dinv[node0 + t + 256] = rsqrtf((float)lcnt[t + 256] + 1.0f);
    }
    __syncthreads();
    for (int e = eb0 + t; e < eb1; e += 256) {
        unsigned v = ebp[e];
        int pos = atomicAdd(&lcur[v & (BNODES - 1)], 1);
        em[pos] = (int)(v >> BSHIFT);
    }
    if (t < nloc) atomicAdd(&gcnt[batch[node0 + t]], 1);
    if (t + 256 < nloc) atomicAdd(&gcnt[batch[node0 + t + 256]], 1);
}

// ---------------------------------------------------------------------------
// Register-blocked dense transform with row scaling, SLICE-MAJOR output:
//   Y16[slice][r][16] = dinv[r] * (X[r] @ W)[slice*16..], packed fp16.
// ---------------------------------------------------------------------------
__global__ __launch_bounds__(256) void gemm128(const float* __restrict__ X,
                                               const float* __restrict__ W,
                                               const float* __restrict__ dinv,
                                               __half* __restrict__ Y, int n) {
    __shared__ float Ws[FDIM * FDIM];          // 64 KiB
    __shared__ float xs[2][BROWS][KCH + 4];    // 10 KiB

    const int tid  = threadIdx.x;
    const int c    = tid & 15;
    const int r    = tid >> 4;
    const int srow = tid >> 2;
    const int skk  = (tid & 3) << 2;
    const int r0   = blockIdx.x * BROWS;

    for (int i = tid; i < FDIM * FDIM; i += 256) Ws[i] = W[i];

    const int grow  = r0 + srow;
    const bool rowok = grow < n;
    const float* xrow = X + (size_t)grow * FDIM + skk;

    float4 v = rowok ? *(const float4*)xrow : float4{0.f, 0.f, 0.f, 0.f};
    *(float4*)&xs[0][srow][skk] = v;
    __syncthreads();

    float accA[4][4], accB[4][4];
#pragma unroll
    for (int m = 0; m < 4; ++m)
#pragma unroll
        for (int i = 0; i < 4; ++i) { accA[m][i] = 0.f; accB[m][i] = 0.f; }

    for (int ch = 0; ch < NCH; ++ch) {
        const int b = ch & 1;
        float4 nv{0.f, 0.f, 0.f, 0.f};
        if (ch + 1 < NCH && rowok)
            nv = *(const float4*)(xrow + (ch + 1) * KCH);
        const int k0 = ch * KCH;
#pragma unroll
        for (int k4 = 0; k4 < KCH; k4 += 4) {
            float4 xv0 = *(const float4*)&xs[b][r][k4];
            float4 xv1 = *(const float4*)&xs[b][r + 16][k4];
            float4 xv2 = *(const float4*)&xs[b][r + 32][k4];
            float4 xv3 = *(const float4*)&xs[b][r + 48][k4];
#define GSTEP(kk, comp)                                                        \
            {                                                                  \
                const float* wp = &Ws[(k0 + k4 + kk) * FDIM + 4 * c];          \
                const float4 w0 = *(const float4*)wp;                          \
                const float4 w1 = *(const float4*)(wp + 64);                   \
                const float xr[4] = {xv0.comp, xv1.comp, xv2.comp, xv3.comp};  \
                _Pragma("unroll")                                              \
                for (int m = 0; m < 4; ++m) {                                  \
                    accA[m][0] = fmaf(xr[m], w0.x, accA[m][0]);                \
                    accA[m][1] = fmaf(xr[m], w0.y, accA[m][1]);                \
                    accA[m][2] = fmaf(xr[m], w0.z, accA[m][2]);                \
                    accB[m][0] = fmaf(xr[m], w1.x, accB[m][0]);                \
                    accB[m][1] = fmaf(xr[m], w1.y, accB[m][1]);                \
                    accB[m][2] = fmaf(xr[m], w1.z, accB[m][2]);                \
                    accB[m][3] = fmaf(xr[m], w1.w, accB[m][3]);                \
                    accA[m][3] = fmaf(xr[m], w0.w, accA[m][3]);                \
                }                                                              \
            }
            GSTEP(0, x) GSTEP(1, y) GSTEP(2, z) GSTEP(3, w)
#undef GSTEP
        }
        if (ch + 1 < NCH)
            *(float4*)&xs[b ^ 1][srow][skk] = nv;
        __syncthreads();
    }

    const size_t N4 = (size_t)n * 4;           // uint2 units per slice
#pragma unroll
    for (int m = 0; m < 4; ++m) {
        int row = r0 + r + 16 * m;
        if (row < n) {
            float dv = dinv[row];
            union { __half2 h[2]; uint2 u; } pa, pb;
            pa.h[0] = __floats2half2_rn(dv * accA[m][0], dv * accA[m][1]);
            pa.h[1] = __floats2half2_rn(dv * accA[m][2], dv * accA[m][3]);
            pb.h[0] = __floats2half2_rn(dv * accB[m][0], dv * accB[m][1]);
            pb.h[1] = __floats2half2_rn(dv * accB[m][2], dv * accB[m][3]);
            // col 4c -> slice c>>2, quad c&3 ; col 64+4c -> slice 4+(c>>2)
            ((uint2*)Y)[(size_t)(c >> 2) * N4 + (size_t)row * 4 + (c & 3)]       = pa.u;
            ((uint2*)Y)[(size_t)(4 + (c >> 2)) * N4 + (size_t)row * 4 + (c & 3)] = pb.u;
        }
    }
}

// ---------------------------------------------------------------------------
// Sliced aggregation: block = (64-node range) x (one 16-feat slice).
// slice = blockIdx % 8 -> same XCD (round-robin dispatch heuristic), so the
// 3.2 MB slice table stays L2-resident. 4 lanes per node (uint2 = 4 feats).
// ---------------------------------------------------------------------------
__device__ __forceinline__ void addv(float4& a, uint2 v) {
    __half2* h = (__half2*)&v;
    float2 f0 = __half22float2(h[0]);
    float2 f1 = __half22float2(h[1]);
    a.x += f0.x; a.y += f0.y; a.z += f1.x; a.w += f1.y;
}

// Layer 1: h1'[slice][d] = dinv[d]*relu(dinv[d]*(sum+self) + b1_slice)
__global__ __launch_bounds__(256) void aggregate_relu_s(
        const __half* __restrict__ hw, const int* __restrict__ rp,
        const int* __restrict__ em, const float* __restrict__ dinv,
        const float* __restrict__ bias, __half* __restrict__ out, int n) {
    const int slice = blockIdx.x & (NSLICE - 1);
    const int node0 = (blockIdx.x >> 3) * 64;
    const int lane  = threadIdx.x & 63;
    const int wave  = threadIdx.x >> 6;
    const int group = lane >> 2;               // 16 nodes per wave
    const int sub   = lane & 3;                // feat quad within slice
    const int node  = node0 + wave * 16 + group;
    if (node >= n) return;
    const uint2* Tb = (const uint2*)hw + (size_t)slice * n * 4;
    int e0 = rp[node], e1 = rp[node + 1];
    float4 a{0.f, 0.f, 0.f, 0.f};
    int e = e0;
    for (; e + 8 <= e1; e += 8) {
        uint2 v[8];
#pragma unroll
        for (int k = 0; k < 8; ++k) v[k] = Tb[(size_t)em[e + k] * 4 + sub];
#pragma unroll
        for (int k = 0; k < 8; ++k) addv(a, v[k]);
    }
    for (; e < e1; ++e) addv(a, Tb[(size_t)em[e] * 4 + sub]);
    addv(a, Tb[(size_t)node * 4 + sub]);       // self loop (pre-scaled row)
    float dv = dinv[node];
    float4 b = ((const float4*)bias)[slice * 4 + sub];
    a.x = dv * fmaxf(fmaf(dv, a.x, b.x), 0.f);
    a.y = dv * fmaxf(fmaf(dv, a.y, b.y), 0.f);
    a.z = dv * fmaxf(fmaf(dv, a.z, b.z), 0.f);
    a.w = dv * fmaxf(fmaf(dv, a.w, b.w), 0.f);
    union { __half2 h[2]; uint2 u; } pk;
    pk.h[0] = __floats2half2_rn(a.x, a.y);
    pk.h[1] = __floats2half2_rn(a.z, a.w);
    ((uint2*)out)[(size_t)slice * n * 4 + (size_t)node * 4 + sub] = pk.u;
}

// Layer 2 pooled (sliced): pool[batch[d]][slice*16..] += dinv[d]*(sum+self).
// LDS run-merge over the block's 64 sorted nodes (4 chunks of 16).
__global__ __launch_bounds__(256) void aggregate_pool_s(
        const __half* __restrict__ h1, const int* __restrict__ rp,
        const int* __restrict__ em, const float* __restrict__ dinv,
        const int* __restrict__ batch, float* __restrict__ pool, int n) {
    __shared__ float4 part[64][4];
    __shared__ int gsh[64];
    const int slice = blockIdx.x & (NSLICE - 1);
    const int node0 = (blockIdx.x >> 3) * 64;
    const int lane  = threadIdx.x & 63;
    const int wave  = threadIdx.x >> 6;
    const int group = lane >> 2;
    const int sub   = lane & 3;
    const int nl    = wave * 16 + group;       // 0..63
    const int node  = node0 + nl;
    const bool valid = node < n;
    const uint2* Tb = (const uint2*)h1 + (size_t)slice * n * 4;
    int e0 = 0, e1 = 0;
    if (valid) { e0 = rp[node]; e1 = rp[node + 1]; }
    float4 a{0.f, 0.f, 0.f, 0.f};
    int e = e0;
    for (; e + 8 <= e1; e += 8) {
        uint2 v[8];
#pragma unroll
        for (int k = 0; k < 8; ++k) v[k] = Tb[(size_t)em[e + k] * 4 + sub];
#pragma unroll
        for (int k = 0; k < 8; ++k) addv(a, v[k]);
    }
    for (; e < e1; ++e) addv(a, Tb[(size_t)em[e] * 4 + sub]);
    if (valid) {
        addv(a, Tb[(size_t)node * 4 + sub]);   // self loop
        float dv = dinv[node];
        a.x *= dv; a.y *= dv; a.z *= dv; a.w *= dv;
    }
    part[nl][sub] = a;
    if (sub == 0) gsh[nl] = valid ? batch[node] : -1;
    __syncthreads();
    if (threadIdx.x < 16) {
        const int msub = threadIdx.x & 3;
        const int chunk = threadIdx.x >> 2;    // 4 chunks x 16 nodes
        float4 acc = part[chunk * 16][msub];
        int g0 = gsh[chunk * 16];
        for (int h = 1; h < 16; ++h) {
            int gh = gsh[chunk * 16 + h];
            float4 pv = part[chunk * 16 + h][msub];
            if (gh == g0) {
                acc.x += pv.x; acc.y += pv.y; acc.z += pv.z; acc.w += pv.w;
            } else {
                if (g0 >= 0) {
                    float* dp = &pool[(size_t)g0 * FDIM + slice * SFEAT + msub * 4];
                    atomicAdd(dp + 0, acc.x); atomicAdd(dp + 1, acc.y);
                    atomicAdd(dp + 2, acc.z); atomicAdd(dp + 3, acc.w);
                }
                g0 = gh;
                acc = pv;
            }
        }
        if (g0 >= 0) {
            float* dp = &pool[(size_t)g0 * FDIM + slice * SFEAT + msub * 4];
            atomicAdd(dp + 0, acc.x); atomicAdd(dp + 1, acc.y);
            atomicAdd(dp + 2, acc.z); atomicAdd(dp + 3, acc.w);
        }
    }
}

// out[g] = (pool[g]/cnt[g]) @ W2 + b2   (b2 suppressed for empty graphs)
__global__ __launch_bounds__(256) void pool_gemm(const float* __restrict__ pool,
                                                 const int* __restrict__ gcnt,
                                                 const float* __restrict__ W2,
                                                 const float* __restrict__ b2,
                                                 float* __restrict__ out, int G) {
    __shared__ float Ws[FDIM * FDIM];   // 64 KiB
    __shared__ float row[2][FDIM];
    for (int i = threadIdx.x; i < FDIM * FDIM; i += 256) Ws[i] = W2[i];
    const int j  = threadIdx.x & 127;
    const int gh = threadIdx.x >> 7;
    for (int g0 = blockIdx.x * 2; g0 < G; g0 += gridDim.x * 2) {
        const int g = g0 + gh;
        __syncthreads();
        int c = 0;
        if (g < G) {
            c = gcnt[g];
            float inv = (c > 0) ? 1.0f / (float)c : 0.0f;
            row[gh][j] = pool[g * FDIM + j] * inv;
        }
        __syncthreads();
        if (g < G) {
            float acc = (c > 0) ? b2[j] : 0.0f;
#pragma unroll
            for (int k = 0; k < FDIM; ++k)
                acc = fmaf(row[gh][k], Ws[k * FDIM + j], acc);
            out[g * FDIM + j] = acc;
        }
    }
}

// ---------------------------------------------------------------------------

extern "C" void kernel_launch(void* const* d_in, const int* in_sizes, int n_in,
                              void* d_out, int out_size, void* d_ws, size_t ws_size,
                              hipStream_t stream) {
    const float* x     = (const float*)d_in[0];
    const int*   ei    = (const int*)d_in[1];
    const int*   batch = (const int*)d_in[2];
    const float* W1    = (const float*)d_in[3];
    const float* b1    = (const float*)d_in[4];
    const float* W2    = (const float*)d_in[5];
    const float* b2    = (const float*)d_in[6];
    float* out = (float*)d_out;

    const int N = in_sizes[0] / FDIM;      // 100000
    const int E = in_sizes[1] / 2;         // 1600000
    const int G = out_size / FDIM;         // 1000
    const int* src = ei;
    const int* dst = ei + E;
    const int nbuck = (N + BNODES - 1) >> BSHIFT;   // 196

    char* p = (char*)d_ws;
    auto alloc = [&](size_t bytes) {
        void* r = (void*)p;
        p += (bytes + 255) & ~(size_t)255;
        return r;
    };
    float*    dinv  = (float*)   alloc((size_t)N * 4);
    int*      rp    = (int*)     alloc((size_t)(N + 1) * 4);
    int*      gcnt  = (int*)     alloc((size_t)G * 4);
    int*      bcnt  = (int*)     alloc(256 * 4);
    int*      bbase = (int*)     alloc(257 * 4);
    int*      bcur  = (int*)     alloc(256 * 4);
    unsigned* ebp   = (unsigned*)alloc((size_t)E * 4);
    int*      em    = (int*)     alloc((size_t)E * 4);
    __half*   hw    = (__half*)  alloc((size_t)N * FDIM * 2);
    __half*   h1    = (__half*)  alloc((size_t)N * FDIM * 2);
    float*    pool  = (float*)   alloc((size_t)G * FDIM * 4);

    hipMemsetAsync(bcnt, 0, 256 * 4, stream);
    hipMemsetAsync(gcnt, 0, (size_t)G * 4, stream);
    hipMemsetAsync(pool, 0, (size_t)G * FDIM * 4, stream);

    // CSR build
    bucket_count<<<1024, 256, 0, stream>>>(dst, bcnt, E);
    bucket_scan<<<1, 256, 0, stream>>>(bcnt, bbase, bcur, rp, E, N, nbuck);
    binscatter<<<(E + EPB - 1) / EPB, 256, 0, stream>>>(src, dst, bcur, ebp, E);
    csr_build<<<nbuck, 256, 0, stream>>>(ebp, bbase, batch, rp, dinv, em, gcnt, N);

    const int GB = (N + BROWS - 1) / BROWS;
    const int AB = ((N + 63) / 64) * NSLICE;   // (node-range, slice) blocks
    // layer 1: hw' = dinv*(x@W1) fp16 slice-major; h1' likewise
    gemm128<<<GB, 256, 0, stream>>>(x, W1, dinv, hw, N);
    aggregate_relu_s<<<AB, 256, 0, stream>>>(hw, rp, em, dinv, b1, h1, N);
    // layer 2: pool(A h1) -> [G,128], then micro-gemm with W2 + b2 + mean div
    aggregate_pool_s<<<AB, 256, 0, stream>>>(h1, rp, em, dinv, batch, pool, N);
    pool_gemm<<<64, 256, 0, stream>>>(pool, gcnt, W2, b2, out, G);
}

// Round 9
// 402.461 us; speedup vs baseline: 1.0995x; 1.0995x over previous
//
#include <hip/hip_runtime.h>
#include <hip/hip_fp16.h>

// N=100000 nodes, E=1600000 edges, F=128, G=1000 graphs.
#define FDIM 128
#define BROWS 64
#define KCH 16
#define NCH (FDIM / KCH)   // 8 chunks
#define BSHIFT 9           // 512 nodes per bucket
#define BNODES 512
#define EPB 4096           // edges per binscatter block

// ---------------------------------------------------------------------------
// CSR build via two-level bucket binning (write-locality aware).
// ---------------------------------------------------------------------------

__global__ __launch_bounds__(256) void bucket_count(const int* __restrict__ dst,
                                                    int* __restrict__ bcnt, int E) {
    __shared__ int lc[256];
    lc[threadIdx.x] = 0;
    __syncthreads();
    for (int e = blockIdx.x * blockDim.x + threadIdx.x; e < E;
         e += gridDim.x * blockDim.x)
        atomicAdd(&lc[dst[e] >> BSHIFT], 1);
    __syncthreads();
    int c = lc[threadIdx.x];
    if (c) atomicAdd(&bcnt[threadIdx.x], c);
}

// single block: exclusive scan of bucket counts -> bbase, bcur; rp[n]=E.
__global__ void bucket_scan(const int* __restrict__ bcnt, int* __restrict__ bbase,
                            int* __restrict__ bcur, int* __restrict__ rp,
                            int E, int n, int nbuck) {
    __shared__ int s[2][256];
    int t = threadIdx.x;
    int v = (t < nbuck) ? bcnt[t] : 0;
    s[0][t] = v;
    __syncthreads();
    int cur = 0;
    for (int off = 1; off < 256; off <<= 1) {
        int x = s[cur][t];
        if (t >= off) x += s[cur][t - off];
        s[cur ^ 1][t] = x;
        cur ^= 1;
        __syncthreads();
    }
    int ex = s[cur][t] - v;
    if (t < nbuck) { bbase[t] = ex; bcur[t] = ex; }
    if (t == 0) { bbase[nbuck] = E; rp[n] = E; }
}

// Bin edges into bucket-ordered u32 buffer ebp[] with block-contiguous runs.
__global__ __launch_bounds__(256) void binscatter(const int* __restrict__ src,
                                                  const int* __restrict__ dst,
                                                  int* __restrict__ bcur,
                                                  unsigned* __restrict__ ebp, int E) {
    __shared__ int lcnt[256];
    __shared__ int gb[256];
    const int t = threadIdx.x;
    const int e0 = blockIdx.x * EPB;
    const int e1 = min(e0 + EPB, E);
    lcnt[t] = 0;
    __syncthreads();
    for (int e = e0 + t; e < e1; e += 256)
        atomicAdd(&lcnt[dst[e] >> BSHIFT], 1);
    __syncthreads();
    int c = lcnt[t];
    if (c) gb[t] = atomicAdd(&bcur[t], c);   // claim contiguous run per bucket
    __syncthreads();
    lcnt[t] = 0;
    __syncthreads();
    for (int e = e0 + t; e < e1; e += 256) {
        int d = dst[e];
        int b = d >> BSHIFT;
        int lo = atomicAdd(&lcnt[b], 1);
        ebp[gb[b] + lo] = ((unsigned)src[e] << BSHIFT) | (unsigned)(d & (BNODES - 1));
    }
}

// One block per bucket: degree count + LDS scan -> rp, dinv; then scatter
// src-only edge list em in CSR order; also graph-count histogram.
__global__ __launch_bounds__(256) void csr_build(const unsigned* __restrict__ ebp,
                                                 const int* __restrict__ bbase,
                                                 const int* __restrict__ batch,
                                                 int* __restrict__ rp,
                                                 float* __restrict__ dinv,
                                                 int* __restrict__ em,
                                                 int* __restrict__ gcnt, int n) {
    __shared__ int lcnt[BNODES];
    __shared__ int s[2][BNODES];
    __shared__ int lcur[BNODES];
    const int t = threadIdx.x;
    const int node0 = blockIdx.x << BSHIFT;
    const int nloc = min(BNODES, n - node0);
    lcnt[t] = 0; lcnt[t + 256] = 0;
    __syncthreads();
    const int eb0 = bbase[blockIdx.x], eb1 = bbase[blockIdx.x + 1];
    for (int e = eb0 + t; e < eb1; e += 256)
        atomicAdd(&lcnt[ebp[e] & (BNODES - 1)], 1);
    __syncthreads();
    s[0][t] = lcnt[t]; s[0][t + 256] = lcnt[t + 256];
    __syncthreads();
    int cur = 0;
    for (int off = 1; off < BNODES; off <<= 1) {
        int x0 = s[cur][t];       if (t >= off)       x0 += s[cur][t - off];
        int x1 = s[cur][t + 256]; if (t + 256 >= off) x1 += s[cur][t + 256 - off];
        s[cur ^ 1][t] = x0; s[cur ^ 1][t + 256] = x1;
        cur ^= 1;
        __syncthreads();
    }
    int ex0 = eb0 + s[cur][t] - lcnt[t];
    int ex1 = eb0 + s[cur][t + 256] - lcnt[t + 256];
    lcur[t] = ex0; lcur[t + 256] = ex1;
    if (t < nloc) {
        rp[node0 + t] = ex0;
        dinv[node0 + t] = rsqrtf((float)lcnt[t] + 1.0f);
    }
    if (t + 256 < nloc) {
        rp[node0 + t + 256] = ex1;
        dinv[node0 + t + 256] = rsqrtf((float)lcnt[t + 256] + 1.0f);
    }
    __syncthreads();
    for (int e = eb0 + t; e < eb1; e += 256) {
        unsigned v = ebp[e];
        int pos = atomicAdd(&lcur[v & (BNODES - 1)], 1);
        em[pos] = (int)(v >> BSHIFT);
    }
    if (t < nloc) atomicAdd(&gcnt[batch[node0 + t]], 1);
    if (t + 256 < nloc) atomicAdd(&gcnt[batch[node0 + t + 256]], 1);
}

// ---------------------------------------------------------------------------
// Register-blocked dense transform with row scaling, ROW-MAJOR fp16 output:
//   Y16[r][128] = dinv[r] * (X[r][128] @ W[128][128]).
// ---------------------------------------------------------------------------
__global__ __launch_bounds__(256) void gemm128(const float* __restrict__ X,
                                               const float* __restrict__ W,
                                               const float* __restrict__ dinv,
                                               __half* __restrict__ Y, int n) {
    __shared__ float Ws[FDIM * FDIM];          // 64 KiB
    __shared__ float xs[2][BROWS][KCH + 4];    // 10 KiB

    const int tid  = threadIdx.x;
    const int c    = tid & 15;
    const int r    = tid >> 4;
    const int srow = tid >> 2;
    const int skk  = (tid & 3) << 2;
    const int r0   = blockIdx.x * BROWS;

    for (int i = tid; i < FDIM * FDIM; i += 256) Ws[i] = W[i];

    const int grow  = r0 + srow;
    const bool rowok = grow < n;
    const float* xrow = X + (size_t)grow * FDIM + skk;

    float4 v = rowok ? *(const float4*)xrow : float4{0.f, 0.f, 0.f, 0.f};
    *(float4*)&xs[0][srow][skk] = v;
    __syncthreads();

    float accA[4][4], accB[4][4];
#pragma unroll
    for (int m = 0; m < 4; ++m)
#pragma unroll
        for (int i = 0; i < 4; ++i) { accA[m][i] = 0.f; accB[m][i] = 0.f; }

    for (int ch = 0; ch < NCH; ++ch) {
        const int b = ch & 1;
        float4 nv{0.f, 0.f, 0.f, 0.f};
        if (ch + 1 < NCH && rowok)
            nv = *(const float4*)(xrow + (ch + 1) * KCH);
        const int k0 = ch * KCH;
#pragma unroll
        for (int k4 = 0; k4 < KCH; k4 += 4) {
            float4 xv0 = *(const float4*)&xs[b][r][k4];
            float4 xv1 = *(const float4*)&xs[b][r + 16][k4];
            float4 xv2 = *(const float4*)&xs[b][r + 32][k4];
            float4 xv3 = *(const float4*)&xs[b][r + 48][k4];
#define GSTEP(kk, comp)                                                        \
            {                                                                  \
                const float* wp = &Ws[(k0 + k4 + kk) * FDIM + 4 * c];          \
                const float4 w0 = *(const float4*)wp;                          \
                const float4 w1 = *(const float4*)(wp + 64);                   \
                const float xr[4] = {xv0.comp, xv1.comp, xv2.comp, xv3.comp};  \
                _Pragma("unroll")                                              \
                for (int m = 0; m < 4; ++m) {                                  \
                    accA[m][0] = fmaf(xr[m], w0.x, accA[m][0]);                \
                    accA[m][1] = fmaf(xr[m], w0.y, accA[m][1]);                \
                    accA[m][2] = fmaf(xr[m], w0.z, accA[m][2]);                \
                    accB[m][0] = fmaf(xr[m], w1.x, accB[m][0]);                \
                    accB[m][1] = fmaf(xr[m], w1.y, accB[m][1]);                \
                    accB[m][2] = fmaf(xr[m], w1.z, accB[m][2]);                \
                    accB[m][3] = fmaf(xr[m], w1.w, accB[m][3]);                \
                    accA[m][3] = fmaf(xr[m], w0.w, accA[m][3]);                \
                }                                                              \
            }
            GSTEP(0, x) GSTEP(1, y) GSTEP(2, z) GSTEP(3, w)
#undef GSTEP
        }
        if (ch + 1 < NCH)
            *(float4*)&xs[b ^ 1][srow][skk] = nv;
        __syncthreads();
    }

#pragma unroll
    for (int m = 0; m < 4; ++m) {
        int row = r0 + r + 16 * m;
        if (row < n) {
            float dv = dinv[row];
            union { __half2 h[2]; uint2 u; } pa, pb;
            pa.h[0] = __floats2half2_rn(dv * accA[m][0], dv * accA[m][1]);
            pa.h[1] = __floats2half2_rn(dv * accA[m][2], dv * accA[m][3]);
            pb.h[0] = __floats2half2_rn(dv * accB[m][0], dv * accB[m][1]);
            pb.h[1] = __floats2half2_rn(dv * accB[m][2], dv * accB[m][3]);
            *(uint2*)&Y[(size_t)row * FDIM + 4 * c]      = pa.u;
            *(uint2*)&Y[(size_t)row * FDIM + 64 + 4 * c] = pb.u;
        }
    }
}

// ---------------------------------------------------------------------------
// Aggregation. A/B test round:
//   aggregate_relu (TEST): 16 lanes/node, uint4 (16 B/lane) -> 4 edges per
//     wave-instruction (half the instruction count, same line count).
//   aggregate_pool (CONTROL): R5 shape, 32 lanes/node, uint2 (8 B/lane).
// ---------------------------------------------------------------------------
__device__ __forceinline__ void addv(float4& a, uint2 v) {
    __half2* h = (__half2*)&v;
    float2 f0 = __half22float2(h[0]);
    float2 f1 = __half22float2(h[1]);
    a.x += f0.x; a.y += f0.y; a.z += f1.x; a.w += f1.y;
}

__device__ __forceinline__ void addv8(float* a, uint4 v) {
    __half2* h = (__half2*)&v;
#pragma unroll
    for (int i = 0; i < 4; ++i) {
        float2 f = __half22float2(h[i]);
        a[2 * i]     += f.x;
        a[2 * i + 1] += f.y;
    }
}

// Layer 1 (uint4 variant): h1'[d] = dinv[d]*relu(dinv[d]*(sum+self)+b1), fp16.
__global__ __launch_bounds__(256) void aggregate_relu(
        const __half* __restrict__ hw, const int* __restrict__ rp,
        const int* __restrict__ em, const float* __restrict__ dinv,
        const float* __restrict__ bias, __half* __restrict__ out, int n) {
    const int l16  = threadIdx.x & 15;
    const int node = blockIdx.x * 16 + (threadIdx.x >> 4);
    if (node >= n) return;
    const uint4* T = (const uint4*)hw;
    int e0 = rp[node], e1 = rp[node + 1];
    float a[8] = {0.f, 0.f, 0.f, 0.f, 0.f, 0.f, 0.f, 0.f};
    int e = e0;
    for (; e + 8 <= e1; e += 8) {
        uint4 v[8];
#pragma unroll
        for (int k = 0; k < 8; ++k) v[k] = T[(size_t)em[e + k] * 16 + l16];
#pragma unroll
        for (int k = 0; k < 8; ++k) addv8(a, v[k]);
    }
    for (; e < e1; ++e) addv8(a, T[(size_t)em[e] * 16 + l16]);
    addv8(a, T[(size_t)node * 16 + l16]);          // self loop (pre-scaled)
    float dv = dinv[node];
    const float4* b4 = (const float4*)bias;
    float4 b0 = b4[l16 * 2], b1 = b4[l16 * 2 + 1];
    float bb[8] = {b0.x, b0.y, b0.z, b0.w, b1.x, b1.y, b1.z, b1.w};
    union { __half2 h[4]; uint4 u; } pk;
#pragma unroll
    for (int i = 0; i < 4; ++i) {
        float r0 = dv * fmaxf(fmaf(dv, a[2 * i],     bb[2 * i]),     0.f);
        float r1 = dv * fmaxf(fmaf(dv, a[2 * i + 1], bb[2 * i + 1]), 0.f);
        pk.h[i] = __floats2half2_rn(r0, r1);
    }
    ((uint4*)out)[(size_t)node * 16 + l16] = pk.u;
}

// Layer 2 pooled (R5 control shape): pool[batch[d]] += dinv[d]*(sum+self).
__global__ __launch_bounds__(256) void aggregate_pool(
        const __half* __restrict__ h1, const int* __restrict__ rp,
        const int* __restrict__ em, const float* __restrict__ dinv,
        const int* __restrict__ batch, float* __restrict__ pool, int n) {
    __shared__ float4 part[8][32];
    __shared__ int gs[8];
    const int lane = threadIdx.x & 31;
    const int half = threadIdx.x >> 5;
    const int node = blockIdx.x * 8 + half;
    const bool valid = node < n;
    const uint2* T = (const uint2*)h1;
    int e0 = 0, e1 = 0;
    if (valid) { e0 = rp[node]; e1 = rp[node + 1]; }
    float4 a{0.f, 0.f, 0.f, 0.f};
    int e = e0;
    for (; e + 16 <= e1; e += 16) {
        uint2 v[16];
#pragma unroll
        for (int k = 0; k < 16; ++k) v[k] = T[(size_t)em[e + k] * 32 + lane];
#pragma unroll
        for (int k = 0; k < 16; ++k) addv(a, v[k]);
    }
    for (; e + 4 <= e1; e += 4) {
        uint2 v[4];
#pragma unroll
        for (int k = 0; k < 4; ++k) v[k] = T[(size_t)em[e + k] * 32 + lane];
#pragma unroll
        for (int k = 0; k < 4; ++k) addv(a, v[k]);
    }
    for (; e < e1; ++e) addv(a, T[(size_t)em[e] * 32 + lane]);
    if (valid) {
        addv(a, T[(size_t)node * 32 + lane]);      // self loop
        float dv = dinv[node];
        a.x *= dv; a.y *= dv; a.z *= dv; a.w *= dv;
    }
    part[half][lane] = a;
    if (lane == 0) gs[half] = valid ? batch[node] : -1;
    __syncthreads();
    if (half == 0) {
        float4 acc = part[0][lane];
        int g0 = gs[0];
#pragma unroll
        for (int h = 1; h < 8; ++h) {
            if (gs[h] == g0) {
                float4 p = part[h][lane];
                acc.x += p.x; acc.y += p.y; acc.z += p.z; acc.w += p.w;
            } else {
                if (g0 >= 0) {
                    float* dstp = &pool[g0 * FDIM + lane * 4];
                    atomicAdd(dstp + 0, acc.x); atomicAdd(dstp + 1, acc.y);
                    atomicAdd(dstp + 2, acc.z); atomicAdd(dstp + 3, acc.w);
                }
                g0 = gs[h];
                acc = part[h][lane];
            }
        }
        if (g0 >= 0) {
            float* dstp = &pool[g0 * FDIM + lane * 4];
            atomicAdd(dstp + 0, acc.x); atomicAdd(dstp + 1, acc.y);
            atomicAdd(dstp + 2, acc.z); atomicAdd(dstp + 3, acc.w);
        }
    }
}

// out[g] = (pool[g]/cnt[g]) @ W2 + b2   (b2 suppressed for empty graphs)
__global__ __launch_bounds__(256) void pool_gemm(const float* __restrict__ pool,
                                                 const int* __restrict__ gcnt,
                                                 const float* __restrict__ W2,
                                                 const float* __restrict__ b2,
                                                 float* __restrict__ out, int G) {
    __shared__ float Ws[FDIM * FDIM];   // 64 KiB
    __shared__ float row[2][FDIM];
    for (int i = threadIdx.x; i < FDIM * FDIM; i += 256) Ws[i] = W2[i];
    const int j  = threadIdx.x & 127;
    const int gh = threadIdx.x >> 7;
    for (int g0 = blockIdx.x * 2; g0 < G; g0 += gridDim.x * 2) {
        const int g = g0 + gh;
        __syncthreads();
        int c = 0;
        if (g < G) {
            c = gcnt[g];
            float inv = (c > 0) ? 1.0f / (float)c : 0.0f;
            row[gh][j] = pool[g * FDIM + j] * inv;
        }
        __syncthreads();
        if (g < G) {
            float acc = (c > 0) ? b2[j] : 0.0f;
#pragma unroll
            for (int k = 0; k < FDIM; ++k)
                acc = fmaf(row[gh][k], Ws[k * FDIM + j], acc);
            out[g * FDIM + j] = acc;
        }
    }
}

// ---------------------------------------------------------------------------

extern "C" void kernel_launch(void* const* d_in, const int* in_sizes, int n_in,
                              void* d_out, int out_size, void* d_ws, size_t ws_size,
                              hipStream_t stream) {
    const float* x     = (const float*)d_in[0];
    const int*   ei    = (const int*)d_in[1];
    const int*   batch = (const int*)d_in[2];
    const float* W1    = (const float*)d_in[3];
    const float* b1    = (const float*)d_in[4];
    const float* W2    = (const float*)d_in[5];
    const float* b2    = (const float*)d_in[6];
    float* out = (float*)d_out;

    const int N = in_sizes[0] / FDIM;      // 100000
    const int E = in_sizes[1] / 2;         // 1600000
    const int G = out_size / FDIM;         // 1000
    const int* src = ei;
    const int* dst = ei + E;
    const int nbuck = (N + BNODES - 1) >> BSHIFT;   // 196

    char* p = (char*)d_ws;
    auto alloc = [&](size_t bytes) {
        void* r = (void*)p;
        p += (bytes + 255) & ~(size_t)255;
        return r;
    };
    float*    dinv  = (float*)   alloc((size_t)N * 4);
    int*      rp    = (int*)     alloc((size_t)(N + 1) * 4);
    // zero-region: gcnt + bcnt + pool contiguous -> single memset
    int*      gcnt  = (int*)     alloc((size_t)G * 4);
    int*      bcnt  = (int*)     alloc(256 * 4);
    float*    pool  = (float*)   alloc((size_t)G * FDIM * 4);
    char*     zend  = p;
    int*      bbase = (int*)     alloc(257 * 4);
    int*      bcur  = (int*)     alloc(256 * 4);
    unsigned* ebp   = (unsigned*)alloc((size_t)E * 4);
    int*      em    = (int*)     alloc((size_t)E * 4);
    __half*   hw    = (__half*)  alloc((size_t)N * FDIM * 2);
    __half*   h1    = (__half*)  alloc((size_t)N * FDIM * 2);

    hipMemsetAsync(gcnt, 0, (size_t)(zend - (char*)gcnt), stream);

    // CSR build
    bucket_count<<<1024, 256, 0, stream>>>(dst, bcnt, E);
    bucket_scan<<<1, 256, 0, stream>>>(bcnt, bbase, bcur, rp, E, N, nbuck);
    binscatter<<<(E + EPB - 1) / EPB, 256, 0, stream>>>(src, dst, bcur, ebp, E);
    csr_build<<<nbuck, 256, 0, stream>>>(ebp, bbase, batch, rp, dinv, em, gcnt, N);

    const int GB = (N + BROWS - 1) / BROWS;
    // layer 1: hw' = dinv*(x@W1) fp16 row-major; h1' = dinv*relu(dinv*agg+b1)
    gemm128<<<GB, 256, 0, stream>>>(x, W1, dinv, hw, N);
    aggregate_relu<<<(N + 15) / 16, 256, 0, stream>>>(hw, rp, em, dinv, b1, h1, N);
    // layer 2: pool(A h1) -> [G,128], then micro-gemm with W2 + b2 + mean div
    aggregate_pool<<<(N + 7) / 8, 256, 0, stream>>>(h1, rp, em, dinv, batch, pool, N);
    pool_gemm<<<64, 256, 0, stream>>>(pool, gcnt, W2, b2, out, G);
}